// Round 2
// baseline (385.057 us; speedup 1.0000x reference)
//
#include <hip/hip_runtime.h>
#include <cstdint>
#include <cstddef>

#define TDIM 4096       // B*S tokens
#define DDIM 1024
#define HDIM 4096
#define EDIM 8
#define CAPD 2048
#define NSLOT 8192      // T*K
#define NROUTERBLK 1024

typedef _Float16 f16;
typedef _Float16 f16x2 __attribute__((ext_vector_type(2)));
typedef _Float16 f16x4 __attribute__((ext_vector_type(4)));
typedef _Float16 f16x8 __attribute__((ext_vector_type(8)));
typedef float f32x4 __attribute__((ext_vector_type(4)));

__device__ __forceinline__ void gload16(const void* g, void* l) {
  __builtin_amdgcn_global_load_lds(
      (const __attribute__((address_space(1))) unsigned int*)g,
      (__attribute__((address_space(3))) unsigned int*)l, 16, 0, 0);
}

// ---------------- transpose + f32->f16 convert: src (E,R,C) -> dst (E,C,R) ----------------
// 64x64 tile, float4 reads, f16x4 writes, [64][65] LDS pad (write-read both <=2-way).
__global__ __launch_bounds__(256)
void transpose_cvt(const float* __restrict__ src, f16* __restrict__ dst, int R, int C) {
  __shared__ float tile[64][65];
  const int e = blockIdx.z;
  const int c0 = blockIdx.x * 64, r0 = blockIdx.y * 64;
  const int tid = threadIdx.x;
  const float* s = src + (size_t)e * R * C;
  f16* d = dst + (size_t)e * R * C;
  #pragma unroll
  for (int p = 0; p < 4; ++p) {
    const int row = p * 16 + (tid >> 4);
    const int col = (tid & 15) * 4;
    float4 v = *(const float4*)(s + (size_t)(r0 + row) * C + c0 + col);
    tile[row][col] = v.x; tile[row][col + 1] = v.y;
    tile[row][col + 2] = v.z; tile[row][col + 3] = v.w;
  }
  __syncthreads();
  #pragma unroll
  for (int p = 0; p < 4; ++p) {
    const int crow = p * 16 + (tid >> 4);   // output row (= source column)
    const int q = (tid & 15) * 4;           // output col (= source row)
    f16x4 o;
    #pragma unroll
    for (int j = 0; j < 4; ++j) o[j] = (f16)tile[q + j][crow];
    *(f16x4*)(d + (size_t)(c0 + crow) * R + r0 + q) = o;
  }
}

// ---------------- router: logits, softmax, top-2, gates, per-block prob sums ----------------
__global__ void router_k(const float* __restrict__ x, const float* __restrict__ rw,
                         int* __restrict__ eidx, float* __restrict__ gates,
                         float* __restrict__ bps) {
  __shared__ float lrw[EDIM * DDIM];   // 32 KiB
  __shared__ float wps[4][EDIM];
  const int tid = threadIdx.x, lane = tid & 63, wv = tid >> 6;
  for (int i = tid; i < EDIM * DDIM; i += 256) lrw[i] = rw[i];
  __syncthreads();
  const int t = blockIdx.x * 4 + wv;
  float acc[EDIM];
  #pragma unroll
  for (int e = 0; e < EDIM; ++e) acc[e] = 0.f;
  const float* xr = x + (size_t)t * DDIM;
  #pragma unroll
  for (int j = 0; j < DDIM / 64; ++j) {
    float xv = xr[j * 64 + lane];
    #pragma unroll
    for (int e = 0; e < EDIM; ++e) acc[e] += xv * lrw[e * DDIM + j * 64 + lane];
  }
  #pragma unroll
  for (int off = 32; off >= 1; off >>= 1) {
    #pragma unroll
    for (int e = 0; e < EDIM; ++e) acc[e] += __shfl_xor(acc[e], off);
  }
  float mx = acc[0];
  #pragma unroll
  for (int e = 1; e < EDIM; ++e) mx = fmaxf(mx, acc[e]);
  float p[EDIM], s = 0.f;
  #pragma unroll
  for (int e = 0; e < EDIM; ++e) { p[e] = expf(acc[e] - mx); s += p[e]; }
  float inv = 1.f / s;
  #pragma unroll
  for (int e = 0; e < EDIM; ++e) p[e] *= inv;
  int i1 = 0; float p1 = p[0];
  #pragma unroll
  for (int e = 1; e < EDIM; ++e) if (p[e] > p1) { p1 = p[e]; i1 = e; }
  int i2 = (i1 == 0) ? 1 : 0; float p2 = p[i2];
  #pragma unroll
  for (int e = 0; e < EDIM; ++e) if (e != i1 && p[e] > p2) { p2 = p[e]; i2 = e; }
  float gs = 1.f / (p1 + p2);
  if (lane == 0) {
    eidx[2 * t] = i1; eidx[2 * t + 1] = i2;
    gates[2 * t] = p1 * gs; gates[2 * t + 1] = p2 * gs;
    #pragma unroll
    for (int e = 0; e < EDIM; ++e) wps[wv][e] = p[e];
  }
  __syncthreads();
  if (tid < EDIM)
    bps[blockIdx.x * EDIM + tid] = wps[0][tid] + wps[1][tid] + wps[2][tid] + wps[3][tid];
}

// ---------------- per-chunk expert histogram (chunk = 256 slots) ----------------
__global__ void count_k(const int* __restrict__ eidx, int* __restrict__ cc) {
  __shared__ int h[EDIM];
  const int tid = threadIdx.x;
  if (tid < EDIM) h[tid] = 0;
  __syncthreads();
  atomicAdd(&h[eidx[blockIdx.x * 256 + tid]], 1);
  __syncthreads();
  if (tid < EDIM) cc[blockIdx.x * EDIM + tid] = h[tid];
}

// ---------------- scan chunks, totals, lb_loss ----------------
__global__ void scan_k(const int* __restrict__ cc, const float* __restrict__ bps,
                       int* __restrict__ cb, int* __restrict__ counts,
                       int* __restrict__ rowsNeeded, float* __restrict__ lb_out) {
  __shared__ float red[32][EDIM];
  __shared__ int cnt_s[EDIM];
  const int tid = threadIdx.x;
  const int e = tid & 7, g = tid >> 3;
  float s = 0.f;
  for (int j = 0; j < 32; ++j) s += bps[(g + 32 * j) * EDIM + e];
  red[g][e] = s;
  __syncthreads();
  for (int st = 16; st >= 1; st >>= 1) {
    if (g < st) red[g][e] += red[g + st][e];
    __syncthreads();
  }
  if (tid < EDIM) {
    int base = 0;
    for (int c = 0; c < 32; ++c) { cb[c * EDIM + tid] = base; base += cc[c * EDIM + tid]; }
    counts[tid] = base;
    rowsNeeded[tid] = base < CAPD ? base : CAPD;
    cnt_s[tid] = base;
  }
  __syncthreads();
  if (tid == 0) {
    float lb = 0.f;
    for (int ee = 0; ee < EDIM; ++ee)
      lb += (red[0][ee] / (float)TDIM) * ((float)cnt_s[ee] / (float)NSLOT);
    lb_out[0] = lb * (float)EDIM;
  }
}

// ---------------- per-slot position via wave ballots (deterministic) ----------------
__global__ void pos_k(const int* __restrict__ eidx, const float* __restrict__ gates,
                      const int* __restrict__ cb, int* __restrict__ posa,
                      float* __restrict__ wslot) {
  __shared__ int wcnt[4][EDIM];
  const int tid = threadIdx.x, lane = tid & 63, wv = tid >> 6;
  const int slot = blockIdx.x * 256 + tid;
  const int e = eidx[slot];
  const unsigned long long below = (1ull << lane) - 1ull;
  int wavepos = 0;
  #pragma unroll
  for (int ee = 0; ee < EDIM; ++ee) {
    unsigned long long m = __ballot(e == ee);
    if (lane == 0) wcnt[wv][ee] = __popcll(m);
    if (e == ee) wavepos = __popcll(m & below);
  }
  __syncthreads();
  int off = 0;
  for (int w = 0; w < wv; ++w) off += wcnt[w][e];
  const int pos = cb[blockIdx.x * EDIM + e] + off + wavepos;
  posa[slot] = pos;
  wslot[slot] = (pos < CAPD) ? gates[slot] : 0.f;
}

// ---------------- scatter token rows -> f16 expert buffers ----------------
__global__ void scatter_k(const float* __restrict__ x, const int* __restrict__ eidx,
                          const int* __restrict__ posa, f16* __restrict__ buf) {
  const int s = blockIdx.x, lane = threadIdx.x;   // 64 threads
  const int p = posa[s];
  if (p >= CAPD) return;
  const int e = eidx[s], tok = s >> 1;
  const float4* src = (const float4*)(x + (size_t)tok * DDIM);
  f16x4* dst = (f16x4*)(buf + ((size_t)e * CAPD + p) * DDIM);
  #pragma unroll
  for (int j = 0; j < DDIM / 4 / 64; ++j) {
    float4 v = src[j * 64 + lane];
    f16x4 o; o.x = (f16)v.x; o.y = (f16)v.y; o.z = (f16)v.z; o.w = (f16)v.w;
    dst[j * 64 + lane] = o;
  }
}

// ---------------- 128x128 f16 MFMA GEMM (m97 structure), B pre-transposed (N,LD) ----------------
// KLEN: K elements this dispatch processes; LD: row stride of A and Bt (full K).
template<int KLEN, int LD, int N, int GELU, int BIAS>
__global__ __launch_bounds__(256)
void gemm_f16(const f16* __restrict__ A, const f16* __restrict__ Bt,
              const float* __restrict__ bias, f16* __restrict__ C,
              const int* __restrict__ rowsNeeded) {
  constexpr int MMAX = CAPD;
  const int e = blockIdx.z, mt = blockIdx.y, nt = blockIdx.x;
  if (mt * 128 >= rowsNeeded[e]) return;
  __shared__ f16 As[128 * 64];
  __shared__ f16 Bs[128 * 64];
  const int tid = threadIdx.x, lane = tid & 63, wv = tid >> 6;
  const int wr = wv >> 1, wc = wv & 1;
  const size_t abase = ((size_t)e * MMAX + (size_t)mt * 128) * LD;
  const size_t bbase = ((size_t)e * N + (size_t)nt * 128) * LD;
  const int srow = tid >> 3;
  const int scol = (tid & 7) * 8;
  const f16* aSrc = A + abase + (size_t)srow * LD + scol;
  const f16* bSrc = Bt + bbase + (size_t)srow * LD + scol;
  char* asDst = (char*)As + wv * 1024;
  char* bsDst = (char*)Bs + wv * 1024;

  f32x4 acc[4][4];
  #pragma unroll
  for (int m = 0; m < 4; ++m)
    #pragma unroll
    for (int n = 0; n < 4; ++n) acc[m][n] = (f32x4){0.f, 0.f, 0.f, 0.f};

  const int ro = lane & 15, ko0 = (lane >> 4) * 8;

  #pragma unroll 1
  for (int kt = 0; kt < KLEN / 64; ++kt) {
    const int k0 = kt * 64;
    __syncthreads();
    #pragma unroll
    for (int i = 0; i < 4; ++i) {
      gload16(aSrc + (size_t)(i * 32) * LD + k0, asDst + i * 4096);
      gload16(bSrc + (size_t)(i * 32) * LD + k0, bsDst + i * 4096);
    }
    __syncthreads();
    #pragma unroll
    for (int kk = 0; kk < 64; kk += 32) {
      f16x8 a[4], b[4];
      #pragma unroll
      for (int m = 0; m < 4; ++m)
        a[m] = *(const f16x8*)(As + (wr * 64 + m * 16 + ro) * 64 + kk + ko0);
      #pragma unroll
      for (int n = 0; n < 4; ++n)
        b[n] = *(const f16x8*)(Bs + (wc * 64 + n * 16 + ro) * 64 + kk + ko0);
      #pragma unroll
      for (int m = 0; m < 4; ++m)
        #pragma unroll
        for (int n = 0; n < 4; ++n)
          acc[m][n] = __builtin_amdgcn_mfma_f32_16x16x32_f16(a[m], b[n], acc[m][n], 0, 0, 0);
    }
  }

  const int rowb = mt * 128 + wr * 64;
  const int colb = nt * 128 + wc * 64;
  #pragma unroll
  for (int m = 0; m < 4; ++m) {
    #pragma unroll
    for (int n = 0; n < 4; ++n) {
      const int col = colb + n * 16 + ro;
      const float bv = BIAS ? bias[e * N + col] : 0.f;
      #pragma unroll
      for (int i = 0; i < 4; ++i) {
        const int row = rowb + m * 16 + (lane >> 4) * 4 + i;
        float v = acc[m][n][i] + bv;
        if (GELU) v = 0.5f * v * (1.f + erff(v * 0.70710678118654752f));
        C[((size_t)e * MMAX + row) * N + col] = (f16)v;
      }
    }
  }
}

// ---------------- combine: out[t] = sum_k wslot * (partA[row] + partB[row]) ----------------
__global__ void combine_k(const f16* __restrict__ pA, const f16* __restrict__ pB,
                          const int* __restrict__ eidx, const int* __restrict__ posa,
                          const float* __restrict__ wslot, float* __restrict__ out) {
  const int t = blockIdx.x, tid = threadIdx.x;
  const int s0 = 2 * t, s1 = 2 * t + 1;
  const int e0 = eidx[s0], e1 = eidx[s1];
  int p0 = posa[s0]; p0 = p0 < CAPD - 1 ? p0 : CAPD - 1;
  int p1 = posa[s1]; p1 = p1 < CAPD - 1 ? p1 : CAPD - 1;
  const float g0 = wslot[s0], g1 = wslot[s1];
  const size_t o0 = ((size_t)e0 * CAPD + p0) * DDIM;
  const size_t o1 = ((size_t)e1 * CAPD + p1) * DDIM;
  const f16x2* r0a = (const f16x2*)(pA + o0);
  const f16x2* r0b = (const f16x2*)(pB + o0);
  const f16x2* r1a = (const f16x2*)(pA + o1);
  const f16x2* r1b = (const f16x2*)(pB + o1);
  float2* o = (float2*)(out + (size_t)t * DDIM);
  #pragma unroll
  for (int j = tid; j < DDIM / 2; j += 256) {
    f16x2 a0 = r0a[j], a1 = r0b[j], b0 = r1a[j], b1 = r1b[j];
    o[j] = make_float2(
        g0 * ((float)a0.x + (float)a1.x) + g1 * ((float)b0.x + (float)b1.x),
        g0 * ((float)a0.y + (float)a1.y) + g1 * ((float)b0.y + (float)b1.y));
  }
}

extern "C" void kernel_launch(void* const* d_in, const int* in_sizes, int n_in,
                              void* d_out, int out_size, void* d_ws, size_t ws_size,
                              hipStream_t stream) {
  (void)in_sizes; (void)n_in; (void)out_size; (void)ws_size;
  const float* x  = (const float*)d_in[0];
  const float* rw = (const float*)d_in[1];
  const float* w1 = (const float*)d_in[2];
  const float* b1 = (const float*)d_in[3];
  const float* w2 = (const float*)d_in[4];
  const float* b2 = (const float*)d_in[5];
  float* out = (float*)d_out;

  char* ws = (char*)d_ws;
  size_t off = 0;
  auto alloc = [&](size_t b) { void* p = ws + off; off += (b + 255) & ~(size_t)255; return p; };
  f16* w1t   = (f16*)alloc((size_t)EDIM * DDIM * HDIM * 2);   // (E,H,D)
  f16* w2t   = (f16*)alloc((size_t)EDIM * DDIM * HDIM * 2);   // (E,D,H)
  f16* buf   = (f16*)alloc((size_t)EDIM * CAPD * DDIM * 2);   // (E,CAP,D)
  f16* hbuf  = (f16*)alloc((size_t)EDIM * CAPD * HDIM * 2);   // (E,CAP,H)
  f16* outeA = (f16*)alloc((size_t)EDIM * CAPD * DDIM * 2);   // split-K partial 0
  f16* outeB = (f16*)alloc((size_t)EDIM * CAPD * DDIM * 2);   // split-K partial 1
  int*   eidx   = (int*)alloc(NSLOT * 4);
  int*   posa   = (int*)alloc(NSLOT * 4);
  float* gatesA = (float*)alloc(NSLOT * 4);
  float* wslotA = (float*)alloc(NSLOT * 4);
  int*   cc     = (int*)alloc(32 * EDIM * 4);
  int*   cb     = (int*)alloc(32 * EDIM * 4);
  int*   counts = (int*)alloc(EDIM * 4);
  int*   rowsN  = (int*)alloc(EDIM * 4);
  float* bps    = (float*)alloc(NROUTERBLK * EDIM * 4);

  // weight conversion (independent of routing chain)
  transpose_cvt<<<dim3(HDIM / 64, DDIM / 64, EDIM), 256, 0, stream>>>(w1, w1t, DDIM, HDIM);
  transpose_cvt<<<dim3(DDIM / 64, HDIM / 64, EDIM), 256, 0, stream>>>(w2, w2t, HDIM, DDIM);

  // routing chain
  router_k<<<NROUTERBLK, 256, 0, stream>>>(x, rw, eidx, gatesA, bps);
  count_k<<<32, 256, 0, stream>>>(eidx, cc);
  scan_k<<<1, 256, 0, stream>>>(cc, bps, cb, counts, rowsN, out + (size_t)TDIM * DDIM);
  pos_k<<<32, 256, 0, stream>>>(eidx, gatesA, cb, posa, wslotA);
  scatter_k<<<NSLOT, 64, 0, stream>>>(x, eidx, posa, buf);

  // expert GEMM 1: (E,CAP,D) x (E,D,H) -> GELU -> (E,CAP,H)
  gemm_f16<DDIM, DDIM, HDIM, 1, 1><<<dim3(HDIM / 128, CAPD / 128, EDIM), 256, 0, stream>>>(
      buf, w1t, b1, hbuf, rowsN);

  // expert GEMM 2, split-K=2: (E,CAP,H) x (E,H,D) -> two f16 partials
  gemm_f16<HDIM / 2, HDIM, DDIM, 0, 1><<<dim3(DDIM / 128, CAPD / 128, EDIM), 256, 0, stream>>>(
      hbuf, w2t, b2, outeA, rowsN);
  gemm_f16<HDIM / 2, HDIM, DDIM, 0, 0><<<dim3(DDIM / 128, CAPD / 128, EDIM), 256, 0, stream>>>(
      hbuf + HDIM / 2, w2t + HDIM / 2, b2, outeB, rowsN);

  // combine
  combine_k<<<TDIM, 256, 0, stream>>>(outeA, outeB, eidx, posa, wslotA, out);
}

// Round 3
// 382.364 us; speedup vs baseline: 1.0070x; 1.0070x over previous
//
#include <hip/hip_runtime.h>
#include <cstdint>
#include <cstddef>

#define TDIM 4096       // B*S tokens
#define DDIM 1024
#define HDIM 4096
#define EDIM 8
#define CAPD 2048
#define NSLOT 8192      // T*K
#define NROUTERBLK 1024

typedef _Float16 f16;
typedef _Float16 f16x2 __attribute__((ext_vector_type(2)));
typedef _Float16 f16x4 __attribute__((ext_vector_type(4)));
typedef _Float16 f16x8 __attribute__((ext_vector_type(8)));
typedef float f32x4 __attribute__((ext_vector_type(4)));

__device__ __forceinline__ void gload16(const void* g, void* l) {
  __builtin_amdgcn_global_load_lds(
      (const __attribute__((address_space(1))) unsigned int*)g,
      (__attribute__((address_space(3))) unsigned int*)l, 16, 0, 0);
}

// fast exact-enough GELU: x * sigmoid(2*sqrt(2/pi)*(x + 0.044715 x^3))
__device__ __forceinline__ float gelu_fast(float x) {
  float y = 1.5957691216057308f * (x + 0.044715f * x * x * x);
  y = fminf(y, 60.f);
  float e = __expf(y);
  return x * e * __builtin_amdgcn_rcpf(e + 1.f);
}

// ---------------- transpose + f32->f16 convert: src (E,R,C) -> dst (E,C,R) ----------------
__global__ __launch_bounds__(256)
void transpose_cvt(const float* __restrict__ src, f16* __restrict__ dst, int R, int C) {
  __shared__ float tile[64][65];
  const int e = blockIdx.z;
  const int c0 = blockIdx.x * 64, r0 = blockIdx.y * 64;
  const int tid = threadIdx.x;
  const float* s = src + (size_t)e * R * C;
  f16* d = dst + (size_t)e * R * C;
  #pragma unroll
  for (int p = 0; p < 4; ++p) {
    const int row = p * 16 + (tid >> 4);
    const int col = (tid & 15) * 4;
    float4 v = *(const float4*)(s + (size_t)(r0 + row) * C + c0 + col);
    tile[row][col] = v.x; tile[row][col + 1] = v.y;
    tile[row][col + 2] = v.z; tile[row][col + 3] = v.w;
  }
  __syncthreads();
  #pragma unroll
  for (int p = 0; p < 4; ++p) {
    const int crow = p * 16 + (tid >> 4);
    const int q = (tid & 15) * 4;
    f16x4 o;
    #pragma unroll
    for (int j = 0; j < 4; ++j) o[j] = (f16)tile[q + j][crow];
    *(f16x4*)(d + (size_t)(c0 + crow) * R + r0 + q) = o;
  }
}

// ---------------- router ----------------
__global__ void router_k(const float* __restrict__ x, const float* __restrict__ rw,
                         int* __restrict__ eidx, float* __restrict__ gates,
                         float* __restrict__ bps) {
  __shared__ float lrw[EDIM * DDIM];
  __shared__ float wps[4][EDIM];
  const int tid = threadIdx.x, lane = tid & 63, wv = tid >> 6;
  for (int i = tid; i < EDIM * DDIM; i += 256) lrw[i] = rw[i];
  __syncthreads();
  const int t = blockIdx.x * 4 + wv;
  float acc[EDIM];
  #pragma unroll
  for (int e = 0; e < EDIM; ++e) acc[e] = 0.f;
  const float* xr = x + (size_t)t * DDIM;
  #pragma unroll
  for (int j = 0; j < DDIM / 64; ++j) {
    float xv = xr[j * 64 + lane];
    #pragma unroll
    for (int e = 0; e < EDIM; ++e) acc[e] += xv * lrw[e * DDIM + j * 64 + lane];
  }
  #pragma unroll
  for (int off = 32; off >= 1; off >>= 1) {
    #pragma unroll
    for (int e = 0; e < EDIM; ++e) acc[e] += __shfl_xor(acc[e], off);
  }
  float mx = acc[0];
  #pragma unroll
  for (int e = 1; e < EDIM; ++e) mx = fmaxf(mx, acc[e]);
  float p[EDIM], s = 0.f;
  #pragma unroll
  for (int e = 0; e < EDIM; ++e) { p[e] = expf(acc[e] - mx); s += p[e]; }
  float inv = 1.f / s;
  #pragma unroll
  for (int e = 0; e < EDIM; ++e) p[e] *= inv;
  int i1 = 0; float p1 = p[0];
  #pragma unroll
  for (int e = 1; e < EDIM; ++e) if (p[e] > p1) { p1 = p[e]; i1 = e; }
  int i2 = (i1 == 0) ? 1 : 0; float p2 = p[i2];
  #pragma unroll
  for (int e = 0; e < EDIM; ++e) if (e != i1 && p[e] > p2) { p2 = p[e]; i2 = e; }
  float gs = 1.f / (p1 + p2);
  if (lane == 0) {
    eidx[2 * t] = i1; eidx[2 * t + 1] = i2;
    gates[2 * t] = p1 * gs; gates[2 * t + 1] = p2 * gs;
    #pragma unroll
    for (int e = 0; e < EDIM; ++e) wps[wv][e] = p[e];
  }
  __syncthreads();
  if (tid < EDIM)
    bps[blockIdx.x * EDIM + tid] = wps[0][tid] + wps[1][tid] + wps[2][tid] + wps[3][tid];
}

// ---------------- per-chunk expert histogram ----------------
__global__ void count_k(const int* __restrict__ eidx, int* __restrict__ cc) {
  __shared__ int h[EDIM];
  const int tid = threadIdx.x;
  if (tid < EDIM) h[tid] = 0;
  __syncthreads();
  atomicAdd(&h[eidx[blockIdx.x * 256 + tid]], 1);
  __syncthreads();
  if (tid < EDIM) cc[blockIdx.x * EDIM + tid] = h[tid];
}

// ---------------- scan chunks, totals, lb_loss ----------------
__global__ void scan_k(const int* __restrict__ cc, const float* __restrict__ bps,
                       int* __restrict__ cb, int* __restrict__ counts,
                       int* __restrict__ rowsNeeded, float* __restrict__ lb_out) {
  __shared__ float red[32][EDIM];
  __shared__ int cnt_s[EDIM];
  const int tid = threadIdx.x;
  const int e = tid & 7, g = tid >> 3;
  float s = 0.f;
  for (int j = 0; j < 32; ++j) s += bps[(g + 32 * j) * EDIM + e];
  red[g][e] = s;
  __syncthreads();
  for (int st = 16; st >= 1; st >>= 1) {
    if (g < st) red[g][e] += red[g + st][e];
    __syncthreads();
  }
  if (tid < EDIM) {
    int base = 0;
    for (int c = 0; c < 32; ++c) { cb[c * EDIM + tid] = base; base += cc[c * EDIM + tid]; }
    counts[tid] = base;
    rowsNeeded[tid] = base < CAPD ? base : CAPD;
    cnt_s[tid] = base;
  }
  __syncthreads();
  if (tid == 0) {
    float lb = 0.f;
    for (int ee = 0; ee < EDIM; ++ee)
      lb += (red[0][ee] / (float)TDIM) * ((float)cnt_s[ee] / (float)NSLOT);
    lb_out[0] = lb * (float)EDIM;
  }
}

// ---------------- per-slot position via wave ballots (deterministic) ----------------
__global__ void pos_k(const int* __restrict__ eidx, const float* __restrict__ gates,
                      const int* __restrict__ cb, int* __restrict__ posa,
                      float* __restrict__ wslot) {
  __shared__ int wcnt[4][EDIM];
  const int tid = threadIdx.x, lane = tid & 63, wv = tid >> 6;
  const int slot = blockIdx.x * 256 + tid;
  const int e = eidx[slot];
  const unsigned long long below = (1ull << lane) - 1ull;
  int wavepos = 0;
  #pragma unroll
  for (int ee = 0; ee < EDIM; ++ee) {
    unsigned long long m = __ballot(e == ee);
    if (lane == 0) wcnt[wv][ee] = __popcll(m);
    if (e == ee) wavepos = __popcll(m & below);
  }
  __syncthreads();
  int off = 0;
  for (int w = 0; w < wv; ++w) off += wcnt[w][e];
  const int pos = cb[blockIdx.x * EDIM + e] + off + wavepos;
  posa[slot] = pos;
  wslot[slot] = (pos < CAPD) ? gates[slot] : 0.f;
}

// ---------------- scatter token rows -> f16 expert buffers ----------------
__global__ void scatter_k(const float* __restrict__ x, const int* __restrict__ eidx,
                          const int* __restrict__ posa, f16* __restrict__ buf) {
  const int s = blockIdx.x, lane = threadIdx.x;
  const int p = posa[s];
  if (p >= CAPD) return;
  const int e = eidx[s], tok = s >> 1;
  const float4* src = (const float4*)(x + (size_t)tok * DDIM);
  f16x4* dst = (f16x4*)(buf + ((size_t)e * CAPD + p) * DDIM);
  #pragma unroll
  for (int j = 0; j < DDIM / 4 / 64; ++j) {
    float4 v = src[j * 64 + lane];
    f16x4 o; o.x = (f16)v.x; o.y = (f16)v.y; o.z = (f16)v.z; o.w = (f16)v.w;
    dst[j * 64 + lane] = o;
  }
}

// ---------------- 128x128 f16 MFMA GEMM, B pre-transposed (N,LD), split-K via blockIdx.z ----------------
// z = e + EDIM*ks; output goes to C + ks*pstride; bias applied only when ks==0.
template<int KLEN, int LD, int N, int GELU>
__global__ __launch_bounds__(256)
void gemm_f16(const f16* __restrict__ A, const f16* __restrict__ Bt,
              const float* __restrict__ bias, f16* __restrict__ C, size_t pstride,
              const int* __restrict__ rowsNeeded) {
  constexpr int MMAX = CAPD;
  const int z = blockIdx.z, e = z & 7, ks = z >> 3;
  const int mt = blockIdx.y, nt = blockIdx.x;
  if (mt * 128 >= rowsNeeded[e]) return;
  __shared__ f16 smem[128 * 128];       // As(16KB) + Bs(16KB), reused as Cs(32KB)
  f16* As = smem;
  f16* Bs = smem + 128 * 64;
  const int tid = threadIdx.x, lane = tid & 63, wv = tid >> 6;
  const int wr = wv >> 1, wc = wv & 1;
  const size_t abase = ((size_t)e * MMAX + (size_t)mt * 128) * LD + (size_t)ks * KLEN;
  const size_t bbase = ((size_t)e * N + (size_t)nt * 128) * LD + (size_t)ks * KLEN;
  const int srow = tid >> 3;
  const int scol = (tid & 7) * 8;
  const f16* aSrc = A + abase + (size_t)srow * LD + scol;
  const f16* bSrc = Bt + bbase + (size_t)srow * LD + scol;
  char* asDst = (char*)As + wv * 1024;
  char* bsDst = (char*)Bs + wv * 1024;

  f32x4 acc[4][4];
  #pragma unroll
  for (int m = 0; m < 4; ++m)
    #pragma unroll
    for (int n = 0; n < 4; ++n) acc[m][n] = (f32x4){0.f, 0.f, 0.f, 0.f};

  const int ro = lane & 15, ko0 = (lane >> 4) * 8;

  #pragma unroll 1
  for (int kt = 0; kt < KLEN / 64; ++kt) {
    const int k0 = kt * 64;
    __syncthreads();
    #pragma unroll
    for (int i = 0; i < 4; ++i) {
      gload16(aSrc + (size_t)(i * 32) * LD + k0, asDst + i * 4096);
      gload16(bSrc + (size_t)(i * 32) * LD + k0, bsDst + i * 4096);
    }
    __syncthreads();
    #pragma unroll
    for (int kk = 0; kk < 64; kk += 32) {
      f16x8 a[4], b[4];
      #pragma unroll
      for (int m = 0; m < 4; ++m)
        a[m] = *(const f16x8*)(As + (wr * 64 + m * 16 + ro) * 64 + kk + ko0);
      #pragma unroll
      for (int n = 0; n < 4; ++n)
        b[n] = *(const f16x8*)(Bs + (wc * 64 + n * 16 + ro) * 64 + kk + ko0);
      #pragma unroll
      for (int m = 0; m < 4; ++m)
        #pragma unroll
        for (int n = 0; n < 4; ++n)
          acc[m][n] = __builtin_amdgcn_mfma_f32_16x16x32_f16(a[m], b[n], acc[m][n], 0, 0, 0);
    }
  }

  // ---- LDS-staged epilogue: bias+GELU -> f16 tile (bank-swizzled) -> coalesced 16B stores
  const int colb = nt * 128 + wc * 64;
  const int q4 = (lane >> 4) * 4, gq = lane >> 4;   // group id 0..3
  float bv[4];
  #pragma unroll
  for (int n = 0; n < 4; ++n)
    bv[n] = (ks == 0) ? bias[e * N + colb + n * 16 + ro] : 0.f;
  __syncthreads();                                   // all waves done reading As/Bs
  f16* Cs = smem;
  #pragma unroll
  for (int m = 0; m < 4; ++m)
    #pragma unroll
    for (int n = 0; n < 4; ++n)
      #pragma unroll
      for (int i = 0; i < 4; ++i) {
        const int row = wr * 64 + m * 16 + q4 + i;
        const int sc = wc * 64 + ((n ^ gq) * 16) + ro;   // XOR-swizzle: conflict-free writes
        float v = acc[m][n][i] + bv[n];
        if (GELU) v = gelu_fast(v);
        Cs[row * 128 + sc] = (f16)v;
      }
  __syncthreads();
  f16* Cp = C + (size_t)ks * pstride;
  #pragma unroll
  for (int p = 0; p < 8; ++p) {
    const int idx = p * 256 + tid;
    const int r = idx >> 4, c = (idx & 15) * 8;
    const int sc = c ^ (((r >> 2) & 3) << 4);            // unswizzle
    f16x8 v = *(const f16x8*)(Cs + r * 128 + sc);
    *(f16x8*)(Cp + ((size_t)e * MMAX + mt * 128 + r) * N + nt * 128 + c) = v;
  }
}

// ---------------- combine: out[t] = sum_k wslot * (partA[row] + partB[row]) ----------------
__global__ void combine_k(const f16* __restrict__ pA, const f16* __restrict__ pB,
                          const int* __restrict__ eidx, const int* __restrict__ posa,
                          const float* __restrict__ wslot, float* __restrict__ out) {
  const int t = blockIdx.x, tid = threadIdx.x;
  const int s0 = 2 * t, s1 = 2 * t + 1;
  const int e0 = eidx[s0], e1 = eidx[s1];
  int p0 = posa[s0]; p0 = p0 < CAPD - 1 ? p0 : CAPD - 1;
  int p1 = posa[s1]; p1 = p1 < CAPD - 1 ? p1 : CAPD - 1;
  const float g0 = wslot[s0], g1 = wslot[s1];
  const size_t o0 = ((size_t)e0 * CAPD + p0) * DDIM;
  const size_t o1 = ((size_t)e1 * CAPD + p1) * DDIM;
  const f16x2* r0a = (const f16x2*)(pA + o0);
  const f16x2* r0b = (const f16x2*)(pB + o0);
  const f16x2* r1a = (const f16x2*)(pA + o1);
  const f16x2* r1b = (const f16x2*)(pB + o1);
  float2* o = (float2*)(out + (size_t)t * DDIM);
  #pragma unroll
  for (int j = tid; j < DDIM / 2; j += 256) {
    f16x2 a0 = r0a[j], a1 = r0b[j], b0 = r1a[j], b1 = r1b[j];
    o[j] = make_float2(
        g0 * ((float)a0.x + (float)a1.x) + g1 * ((float)b0.x + (float)b1.x),
        g0 * ((float)a0.y + (float)a1.y) + g1 * ((float)b0.y + (float)b1.y));
  }
}

extern "C" void kernel_launch(void* const* d_in, const int* in_sizes, int n_in,
                              void* d_out, int out_size, void* d_ws, size_t ws_size,
                              hipStream_t stream) {
  (void)in_sizes; (void)n_in; (void)out_size; (void)ws_size;
  const float* x  = (const float*)d_in[0];
  const float* rw = (const float*)d_in[1];
  const float* w1 = (const float*)d_in[2];
  const float* b1 = (const float*)d_in[3];
  const float* w2 = (const float*)d_in[4];
  const float* b2 = (const float*)d_in[5];
  float* out = (float*)d_out;

  char* ws = (char*)d_ws;
  size_t off = 0;
  auto alloc = [&](size_t b) { void* p = ws + off; off += (b + 255) & ~(size_t)255; return p; };
  f16* w1t   = (f16*)alloc((size_t)EDIM * DDIM * HDIM * 2);   // (E,H,D)
  f16* w2t   = (f16*)alloc((size_t)EDIM * DDIM * HDIM * 2);   // (E,D,H)
  f16* buf   = (f16*)alloc((size_t)EDIM * CAPD * DDIM * 2);   // (E,CAP,D)
  f16* hbuf  = (f16*)alloc((size_t)EDIM * CAPD * HDIM * 2);   // (E,CAP,H)
  const size_t PSTRIDE = (size_t)EDIM * CAPD * DDIM;
  f16* outeA = (f16*)alloc(PSTRIDE * 2);                       // split-K partial 0
  f16* outeB = (f16*)alloc(PSTRIDE * 2);                       // split-K partial 1 (contiguous)
  int*   eidx   = (int*)alloc(NSLOT * 4);
  int*   posa   = (int*)alloc(NSLOT * 4);
  float* gatesA = (float*)alloc(NSLOT * 4);
  float* wslotA = (float*)alloc(NSLOT * 4);
  int*   cc     = (int*)alloc(32 * EDIM * 4);
  int*   cb     = (int*)alloc(32 * EDIM * 4);
  int*   counts = (int*)alloc(EDIM * 4);
  int*   rowsN  = (int*)alloc(EDIM * 4);
  float* bps    = (float*)alloc(NROUTERBLK * EDIM * 4);
  (void)outeB;

  // weight conversion (independent of routing chain)
  transpose_cvt<<<dim3(HDIM / 64, DDIM / 64, EDIM), 256, 0, stream>>>(w1, w1t, DDIM, HDIM);
  transpose_cvt<<<dim3(DDIM / 64, HDIM / 64, EDIM), 256, 0, stream>>>(w2, w2t, HDIM, DDIM);

  // routing chain
  router_k<<<NROUTERBLK, 256, 0, stream>>>(x, rw, eidx, gatesA, bps);
  count_k<<<32, 256, 0, stream>>>(eidx, cc);
  scan_k<<<1, 256, 0, stream>>>(cc, bps, cb, counts, rowsN, out + (size_t)TDIM * DDIM);
  pos_k<<<32, 256, 0, stream>>>(eidx, gatesA, cb, posa, wslotA);
  scatter_k<<<NSLOT, 64, 0, stream>>>(x, eidx, posa, buf);

  // expert GEMM 1: (E,CAP,D) x (E,D,H) -> GELU -> (E,CAP,H)
  gemm_f16<DDIM, DDIM, HDIM, 1><<<dim3(HDIM / 128, CAPD / 128, EDIM), 256, 0, stream>>>(
      buf, w1t, b1, hbuf, 0, rowsN);

  // expert GEMM 2, split-K=2 in ONE dispatch (z = e + 8*ks)
  gemm_f16<HDIM / 2, HDIM, DDIM, 0><<<dim3(DDIM / 128, CAPD / 128, EDIM * 2), 256, 0, stream>>>(
      hbuf, w2t, b2, outeA, PSTRIDE, rowsN);

  // combine
  combine_k<<<TDIM, 256, 0, stream>>>(outeA, outeA + PSTRIDE, eidx, posa, wslotA, out);
}

// Round 4
// 367.361 us; speedup vs baseline: 1.0482x; 1.0408x over previous
//
#include <hip/hip_runtime.h>
#include <cstdint>
#include <cstddef>

#define TDIM 4096       // B*S tokens
#define DDIM 1024
#define HDIM 4096
#define EDIM 8
#define CAPD 2048
#define NSLOT 8192      // T*K
#define NROUTERBLK 1024

typedef _Float16 f16;
typedef _Float16 f16x2 __attribute__((ext_vector_type(2)));
typedef _Float16 f16x4 __attribute__((ext_vector_type(4)));
typedef _Float16 f16x8 __attribute__((ext_vector_type(8)));
typedef float f32x4 __attribute__((ext_vector_type(4)));

__device__ __forceinline__ void gload16(const void* g, void* l) {
  __builtin_amdgcn_global_load_lds(
      (const __attribute__((address_space(1))) unsigned int*)g,
      (__attribute__((address_space(3))) unsigned int*)l, 16, 0, 0);
}

__device__ __forceinline__ float gelu_fast(float x) {
  float y = 1.5957691216057308f * (x + 0.044715f * x * x * x);
  y = fminf(y, 60.f);
  float e = __expf(y);
  return x * e * __builtin_amdgcn_rcpf(e + 1.f);
}

#define MEMFENCE asm volatile("" ::: "memory")

// ---------------- transpose + f32->f16 convert: src (E,R,C) -> dst (E,C,R) ----------------
__global__ __launch_bounds__(256)
void transpose_cvt(const float* __restrict__ src, f16* __restrict__ dst, int R, int C) {
  __shared__ float tile[64][65];
  const int e = blockIdx.z;
  const int c0 = blockIdx.x * 64, r0 = blockIdx.y * 64;
  const int tid = threadIdx.x;
  const float* s = src + (size_t)e * R * C;
  f16* d = dst + (size_t)e * R * C;
  #pragma unroll
  for (int p = 0; p < 4; ++p) {
    const int row = p * 16 + (tid >> 4);
    const int col = (tid & 15) * 4;
    float4 v = *(const float4*)(s + (size_t)(r0 + row) * C + c0 + col);
    tile[row][col] = v.x; tile[row][col + 1] = v.y;
    tile[row][col + 2] = v.z; tile[row][col + 3] = v.w;
  }
  __syncthreads();
  #pragma unroll
  for (int p = 0; p < 4; ++p) {
    const int crow = p * 16 + (tid >> 4);
    const int q = (tid & 15) * 4;
    f16x4 o;
    #pragma unroll
    for (int j = 0; j < 4; ++j) o[j] = (f16)tile[q + j][crow];
    *(f16x4*)(d + (size_t)(c0 + crow) * R + r0 + q) = o;
  }
}

// ---------------- router ----------------
__global__ void router_k(const float* __restrict__ x, const float* __restrict__ rw,
                         int* __restrict__ eidx, float* __restrict__ gates,
                         float* __restrict__ bps) {
  __shared__ float lrw[EDIM * DDIM];
  __shared__ float wps[4][EDIM];
  const int tid = threadIdx.x, lane = tid & 63, wv = tid >> 6;
  for (int i = tid; i < EDIM * DDIM; i += 256) lrw[i] = rw[i];
  __syncthreads();
  const int t = blockIdx.x * 4 + wv;
  float acc[EDIM];
  #pragma unroll
  for (int e = 0; e < EDIM; ++e) acc[e] = 0.f;
  const float* xr = x + (size_t)t * DDIM;
  #pragma unroll
  for (int j = 0; j < DDIM / 64; ++j) {
    float xv = xr[j * 64 + lane];
    #pragma unroll
    for (int e = 0; e < EDIM; ++e) acc[e] += xv * lrw[e * DDIM + j * 64 + lane];
  }
  #pragma unroll
  for (int off = 32; off >= 1; off >>= 1) {
    #pragma unroll
    for (int e = 0; e < EDIM; ++e) acc[e] += __shfl_xor(acc[e], off);
  }
  float mx = acc[0];
  #pragma unroll
  for (int e = 1; e < EDIM; ++e) mx = fmaxf(mx, acc[e]);
  float p[EDIM], s = 0.f;
  #pragma unroll
  for (int e = 0; e < EDIM; ++e) { p[e] = expf(acc[e] - mx); s += p[e]; }
  float inv = 1.f / s;
  #pragma unroll
  for (int e = 0; e < EDIM; ++e) p[e] *= inv;
  int i1 = 0; float p1 = p[0];
  #pragma unroll
  for (int e = 1; e < EDIM; ++e) if (p[e] > p1) { p1 = p[e]; i1 = e; }
  int i2 = (i1 == 0) ? 1 : 0; float p2 = p[i2];
  #pragma unroll
  for (int e = 0; e < EDIM; ++e) if (e != i1 && p[e] > p2) { p2 = p[e]; i2 = e; }
  float gs = 1.f / (p1 + p2);
  if (lane == 0) {
    eidx[2 * t] = i1; eidx[2 * t + 1] = i2;
    gates[2 * t] = p1 * gs; gates[2 * t + 1] = p2 * gs;
    #pragma unroll
    for (int e = 0; e < EDIM; ++e) wps[wv][e] = p[e];
  }
  __syncthreads();
  if (tid < EDIM)
    bps[blockIdx.x * EDIM + tid] = wps[0][tid] + wps[1][tid] + wps[2][tid] + wps[3][tid];
}

// ---------------- per-chunk expert histogram ----------------
__global__ void count_k(const int* __restrict__ eidx, int* __restrict__ cc) {
  __shared__ int h[EDIM];
  const int tid = threadIdx.x;
  if (tid < EDIM) h[tid] = 0;
  __syncthreads();
  atomicAdd(&h[eidx[blockIdx.x * 256 + tid]], 1);
  __syncthreads();
  if (tid < EDIM) cc[blockIdx.x * EDIM + tid] = h[tid];
}

// ---------------- scan chunks, totals, lb_loss ----------------
__global__ void scan_k(const int* __restrict__ cc, const float* __restrict__ bps,
                       int* __restrict__ cb, int* __restrict__ counts,
                       int* __restrict__ rowsNeeded, float* __restrict__ lb_out) {
  __shared__ float red[32][EDIM];
  __shared__ int cnt_s[EDIM];
  const int tid = threadIdx.x;
  const int e = tid & 7, g = tid >> 3;
  float s = 0.f;
  for (int j = 0; j < 32; ++j) s += bps[(g + 32 * j) * EDIM + e];
  red[g][e] = s;
  __syncthreads();
  for (int st = 16; st >= 1; st >>= 1) {
    if (g < st) red[g][e] += red[g + st][e];
    __syncthreads();
  }
  if (tid < EDIM) {
    int base = 0;
    for (int c = 0; c < 32; ++c) { cb[c * EDIM + tid] = base; base += cc[c * EDIM + tid]; }
    counts[tid] = base;
    rowsNeeded[tid] = base < CAPD ? base : CAPD;
    cnt_s[tid] = base;
  }
  __syncthreads();
  if (tid == 0) {
    float lb = 0.f;
    for (int ee = 0; ee < EDIM; ++ee)
      lb += (red[0][ee] / (float)TDIM) * ((float)cnt_s[ee] / (float)NSLOT);
    lb_out[0] = lb * (float)EDIM;
  }
}

// ---------------- per-slot position via wave ballots (deterministic) ----------------
__global__ void pos_k(const int* __restrict__ eidx, const float* __restrict__ gates,
                      const int* __restrict__ cb, int* __restrict__ posa,
                      float* __restrict__ wslot) {
  __shared__ int wcnt[4][EDIM];
  const int tid = threadIdx.x, lane = tid & 63, wv = tid >> 6;
  const int slot = blockIdx.x * 256 + tid;
  const int e = eidx[slot];
  const unsigned long long below = (1ull << lane) - 1ull;
  int wavepos = 0;
  #pragma unroll
  for (int ee = 0; ee < EDIM; ++ee) {
    unsigned long long m = __ballot(e == ee);
    if (lane == 0) wcnt[wv][ee] = __popcll(m);
    if (e == ee) wavepos = __popcll(m & below);
  }
  __syncthreads();
  int off = 0;
  for (int w = 0; w < wv; ++w) off += wcnt[w][e];
  const int pos = cb[blockIdx.x * EDIM + e] + off + wavepos;
  posa[slot] = pos;
  wslot[slot] = (pos < CAPD) ? gates[slot] : 0.f;
}

// ---------------- scatter token rows -> f16 expert buffers ----------------
__global__ void scatter_k(const float* __restrict__ x, const int* __restrict__ eidx,
                          const int* __restrict__ posa, f16* __restrict__ buf) {
  const int s = blockIdx.x, lane = threadIdx.x;
  const int p = posa[s];
  if (p >= CAPD) return;
  const int e = eidx[s], tok = s >> 1;
  const float4* src = (const float4*)(x + (size_t)tok * DDIM);
  f16x4* dst = (f16x4*)(buf + ((size_t)e * CAPD + p) * DDIM);
  #pragma unroll
  for (int j = 0; j < DDIM / 4 / 64; ++j) {
    float4 v = src[j * 64 + lane];
    f16x4 o; o.x = (f16)v.x; o.y = (f16)v.y; o.z = (f16)v.z; o.w = (f16)v.w;
    dst[j * 64 + lane] = o;
  }
}

// ============ 256x256 f16 MFMA GEMM, phase-split dbuf schedule (T2+T3+T4+T5) ============
// B pre-transposed (N,LD). z = e + EDIM*ks (split-K); bias only when ks==0.
// 8 waves (2M x 4N), per-wave 128x64 output. LDS 128KB = 2 dbuf x (A 32KB + B 32KB).
// T2 swizzle: LDS linear dest, inverse-swizzled global src, swizzled reads (slot ^= row&7).
template<int KLEN, int LD, int N, int GELU>
__global__ __launch_bounds__(512, 1)
void gemm256(const f16* __restrict__ A, const f16* __restrict__ Bt,
             const float* __restrict__ bias, f16* __restrict__ C, size_t pstride,
             const int* __restrict__ rowsNeeded) {
  constexpr int NKT = KLEN / 64;
  __shared__ f16 smem[4 * 16384];          // A0 | B0 | A1 | B1, 32KB each
  const int z = blockIdx.z, e = z & 7, ks = z >> 3;
  const int mt = blockIdx.y, nt = blockIdx.x;
  if (mt * 256 >= rowsNeeded[e]) return;
  const int tid = threadIdx.x, lane = tid & 63, wv = tid >> 6;
  const int wr = wv >> 2, wc = wv & 3;     // 2 x 4 wave grid
  f16* const As0 = smem;
  f16* const Bs0 = smem + 16384;
  f16* const As1 = smem + 2 * 16384;
  f16* const Bs1 = smem + 3 * 16384;
  const size_t abase = ((size_t)e * CAPD + (size_t)mt * 256) * LD + (size_t)ks * KLEN;
  const size_t bbase = ((size_t)e * N + (size_t)nt * 256) * LD + (size_t)ks * KLEN;

  // staging: chunk idx = i*512+tid covers LDS bytes idx*16; row=idx>>3, slot=idx&7.
  // global src column pre-swizzled: (slot ^ (row&7))*8  (involution; read undoes it)
  const f16* aSrcB[4]; const f16* bSrcB[4];
  #pragma unroll
  for (int i = 0; i < 4; ++i) {
    const int idx = i * 512 + tid, row = idx >> 3, slot = idx & 7;
    aSrcB[i] = A + abase + (size_t)row * LD + (slot ^ (row & 7)) * 8;
    bSrcB[i] = Bt + bbase + (size_t)row * LD + (slot ^ (row & 7)) * 8;
  }
  const int ldsOff = wv * 1024;            // wave-uniform byte base (lane*16 added by HW)

  const int ro = lane & 15, q4 = (lane >> 4) * 4, ko0 = (lane >> 4) * 8;

  f32x4 acc[8][4];
  #pragma unroll
  for (int m = 0; m < 8; ++m)
    #pragma unroll
    for (int n = 0; n < 4; ++n) acc[m][n] = (f32x4){0.f, 0.f, 0.f, 0.f};

  // ---- prologue: stage tiles 0 and 1
  #pragma unroll
  for (int i = 0; i < 4; ++i) gload16(aSrcB[i], (char*)As0 + i * 8192 + ldsOff);
  #pragma unroll
  for (int i = 0; i < 4; ++i) gload16(bSrcB[i], (char*)Bs0 + i * 8192 + ldsOff);
  #pragma unroll
  for (int i = 0; i < 4; ++i) gload16(aSrcB[i] + 64, (char*)As1 + i * 8192 + ldsOff);
  #pragma unroll
  for (int i = 0; i < 4; ++i) gload16(bSrcB[i] + 64, (char*)Bs1 + i * 8192 + ldsOff);
  asm volatile("s_waitcnt vmcnt(8)" ::: "memory");   // tile 0 landed (per-wave)
  __builtin_amdgcn_s_barrier(); MEMFENCE;            // all waves' tile-0 writes visible

  // swizzled frag read: row r, k element k0 (multiple of 8)
  auto ldfrag = [&](const f16* base, int r, int k0) -> f16x8 {
    return *(const f16x8*)((const char*)base + r * 128 + ((k0 * 2) ^ ((r & 7) << 4)));
  };

  int cur = 0;
  #pragma unroll 1
  for (int kt = 0; kt < NKT; ++kt) {
    const f16* Ab = cur ? As1 : As0;
    const f16* Bb = cur ? Bs1 : Bs0;
    f16x8 af[4][2], bf0[2][2], bf1[2][2];
    // ---- P1: read A-half0 + B-half0; MFMA quadrant (m0-3, n0-1)
    #pragma unroll
    for (int m = 0; m < 4; ++m)
      #pragma unroll
      for (int k = 0; k < 2; ++k) af[m][k] = ldfrag(Ab, wr * 128 + m * 16 + ro, k * 32 + ko0);
    #pragma unroll
    for (int n = 0; n < 2; ++n)
      #pragma unroll
      for (int k = 0; k < 2; ++k) bf0[n][k] = ldfrag(Bb, wc * 64 + n * 16 + ro, k * 32 + ko0);
    __builtin_amdgcn_s_barrier();
    asm volatile("s_waitcnt lgkmcnt(0)" ::: "memory");
    __builtin_amdgcn_s_setprio(1);
    #pragma unroll
    for (int m = 0; m < 4; ++m)
      #pragma unroll
      for (int n = 0; n < 2; ++n)
        #pragma unroll
        for (int k = 0; k < 2; ++k)
          acc[m][n] = __builtin_amdgcn_mfma_f32_16x16x32_f16(af[m][k], bf0[n][k], acc[m][n], 0, 0, 0);
    __builtin_amdgcn_s_setprio(0);
    __builtin_amdgcn_s_barrier(); MEMFENCE;
    // ---- P2: read B-half1; MFMA quadrant (m0-3, n2-3)
    #pragma unroll
    for (int n = 0; n < 2; ++n)
      #pragma unroll
      for (int k = 0; k < 2; ++k) bf1[n][k] = ldfrag(Bb, wc * 64 + 32 + n * 16 + ro, k * 32 + ko0);
    __builtin_amdgcn_s_barrier();
    asm volatile("s_waitcnt lgkmcnt(0)" ::: "memory");
    __builtin_amdgcn_s_setprio(1);
    #pragma unroll
    for (int m = 0; m < 4; ++m)
      #pragma unroll
      for (int n = 0; n < 2; ++n)
        #pragma unroll
        for (int k = 0; k < 2; ++k)
          acc[m][2 + n] = __builtin_amdgcn_mfma_f32_16x16x32_f16(af[m][k], bf1[n][k], acc[m][2 + n], 0, 0, 0);
    __builtin_amdgcn_s_setprio(0);
    __builtin_amdgcn_s_barrier(); MEMFENCE;
    // ---- P3: read A-half1 (reuse af regs); MFMA quadrant (m4-7, n2-3)
    #pragma unroll
    for (int m = 0; m < 4; ++m)
      #pragma unroll
      for (int k = 0; k < 2; ++k) af[m][k] = ldfrag(Ab, wr * 128 + 64 + m * 16 + ro, k * 32 + ko0);
    __builtin_amdgcn_s_barrier();
    asm volatile("s_waitcnt lgkmcnt(0)" ::: "memory");
    __builtin_amdgcn_s_setprio(1);
    #pragma unroll
    for (int m = 0; m < 4; ++m)
      #pragma unroll
      for (int n = 0; n < 2; ++n)
        #pragma unroll
        for (int k = 0; k < 2; ++k)
          acc[4 + m][2 + n] = __builtin_amdgcn_mfma_f32_16x16x32_f16(af[m][k], bf1[n][k], acc[4 + m][2 + n], 0, 0, 0);
    __builtin_amdgcn_s_setprio(0);
    __builtin_amdgcn_s_barrier(); MEMFENCE;
    // ---- P4: no reads; MFMA quadrant (m4-7, n0-1)
    __builtin_amdgcn_s_setprio(1);
    #pragma unroll
    for (int m = 0; m < 4; ++m)
      #pragma unroll
      for (int n = 0; n < 2; ++n)
        #pragma unroll
        for (int k = 0; k < 2; ++k)
          acc[4 + m][n] = __builtin_amdgcn_mfma_f32_16x16x32_f16(af[m][k], bf0[n][k], acc[4 + m][n], 0, 0, 0);
    __builtin_amdgcn_s_setprio(0);
    // ---- tile boundary: all waves done reading buf[cur]
    __builtin_amdgcn_s_barrier(); MEMFENCE;
    if (kt + 2 < NKT) {                     // stage kt+2 into buf[cur]
      const int ko = (kt + 2) * 64;
      char* aD = (char*)(cur ? As1 : As0);
      char* bD = (char*)(cur ? Bs1 : Bs0);
      #pragma unroll
      for (int i = 0; i < 4; ++i) gload16(aSrcB[i] + ko, aD + i * 8192 + ldsOff);
      #pragma unroll
      for (int i = 0; i < 4; ++i) gload16(bSrcB[i] + ko, bD + i * 8192 + ldsOff);
    }
    if (kt + 1 < NKT) {
      if (kt + 2 < NKT) asm volatile("s_waitcnt vmcnt(8)" ::: "memory");
      else              asm volatile("s_waitcnt vmcnt(0)" ::: "memory");
      __builtin_amdgcn_s_barrier(); MEMFENCE;
    }
    cur ^= 1;
  }

  // ---- epilogue: per-wave LDS region (16KB), swizzled conflict-free, coalesced stores
  float bv[4];
  #pragma unroll
  for (int n = 0; n < 4; ++n)
    bv[n] = (ks == 0) ? bias[e * N + nt * 256 + wc * 64 + n * 16 + ro] : 0.f;
  f16* Ct = smem + wv * 8192;               // [128][64] f16, col-byte ^= ((row>>2)&3)<<5
  #pragma unroll
  for (int m = 0; m < 8; ++m)
    #pragma unroll
    for (int n = 0; n < 4; ++n)
      #pragma unroll
      for (int i = 0; i < 4; ++i) {
        const int row = m * 16 + q4 + i;
        float v = acc[m][n][i] + bv[n];
        if (GELU) v = gelu_fast(v);
        *(f16*)((char*)Ct + row * 128 + ((((n * 16 + ro) * 2)) ^ (((row >> 2) & 3) << 5))) = (f16)v;
      }
  asm volatile("s_waitcnt lgkmcnt(0)" ::: "memory");
  f16* Cp = C + (size_t)ks * pstride;
  const size_t crow0 = (size_t)e * CAPD + mt * 256 + wr * 128;
  const int ccol0 = nt * 256 + wc * 64;
  #pragma unroll
  for (int j = 0; j < 16; ++j) {
    const int idx = j * 64 + lane;
    const int r = idx >> 3, c2 = (idx & 7) * 16;
    f16x8 v = *(const f16x8*)((const char*)Ct + r * 128 + (c2 ^ (((r >> 2) & 3) << 5)));
    *(f16x8*)(Cp + (crow0 + r) * N + ccol0 + (idx & 7) * 8) = v;
  }
}

// ---------------- combine: out[t] = sum_k wslot * (partA[row] + partB[row]) ----------------
__global__ void combine_k(const f16* __restrict__ pA, const f16* __restrict__ pB,
                          const int* __restrict__ eidx, const int* __restrict__ posa,
                          const float* __restrict__ wslot, float* __restrict__ out) {
  const int t = blockIdx.x, tid = threadIdx.x;
  const int s0 = 2 * t, s1 = 2 * t + 1;
  const int e0 = eidx[s0], e1 = eidx[s1];
  int p0 = posa[s0]; p0 = p0 < CAPD - 1 ? p0 : CAPD - 1;
  int p1 = posa[s1]; p1 = p1 < CAPD - 1 ? p1 : CAPD - 1;
  const float g0 = wslot[s0], g1 = wslot[s1];
  const size_t o0 = ((size_t)e0 * CAPD + p0) * DDIM;
  const size_t o1 = ((size_t)e1 * CAPD + p1) * DDIM;
  const f16x2* r0a = (const f16x2*)(pA + o0);
  const f16x2* r0b = (const f16x2*)(pB + o0);
  const f16x2* r1a = (const f16x2*)(pA + o1);
  const f16x2* r1b = (const f16x2*)(pB + o1);
  float2* o = (float2*)(out + (size_t)t * DDIM);
  #pragma unroll
  for (int j = tid; j < DDIM / 2; j += 256) {
    f16x2 a0 = r0a[j], a1 = r0b[j], b0 = r1a[j], b1 = r1b[j];
    o[j] = make_float2(
        g0 * ((float)a0.x + (float)a1.x) + g1 * ((float)b0.x + (float)b1.x),
        g0 * ((float)a0.y + (float)a1.y) + g1 * ((float)b0.y + (float)b1.y));
  }
}

extern "C" void kernel_launch(void* const* d_in, const int* in_sizes, int n_in,
                              void* d_out, int out_size, void* d_ws, size_t ws_size,
                              hipStream_t stream) {
  (void)in_sizes; (void)n_in; (void)out_size; (void)ws_size;
  const float* x  = (const float*)d_in[0];
  const float* rw = (const float*)d_in[1];
  const float* w1 = (const float*)d_in[2];
  const float* b1 = (const float*)d_in[3];
  const float* w2 = (const float*)d_in[4];
  const float* b2 = (const float*)d_in[5];
  float* out = (float*)d_out;

  char* ws = (char*)d_ws;
  size_t off = 0;
  auto alloc = [&](size_t b) { void* p = ws + off; off += (b + 255) & ~(size_t)255; return p; };
  f16* w1t   = (f16*)alloc((size_t)EDIM * DDIM * HDIM * 2);   // (E,H,D)
  f16* w2t   = (f16*)alloc((size_t)EDIM * DDIM * HDIM * 2);   // (E,D,H)
  f16* buf   = (f16*)alloc((size_t)EDIM * CAPD * DDIM * 2);   // (E,CAP,D)
  f16* hbuf  = (f16*)alloc((size_t)EDIM * CAPD * HDIM * 2);   // (E,CAP,H)
  const size_t PSTRIDE = (size_t)EDIM * CAPD * DDIM;
  f16* outeA = (f16*)alloc(PSTRIDE * 2);                       // split-K partial 0
  f16* outeB = (f16*)alloc(PSTRIDE * 2);                       // split-K partial 1 (contiguous)
  int*   eidx   = (int*)alloc(NSLOT * 4);
  int*   posa   = (int*)alloc(NSLOT * 4);
  float* gatesA = (float*)alloc(NSLOT * 4);
  float* wslotA = (float*)alloc(NSLOT * 4);
  int*   cc     = (int*)alloc(32 * EDIM * 4);
  int*   cb     = (int*)alloc(32 * EDIM * 4);
  int*   counts = (int*)alloc(EDIM * 4);
  int*   rowsN  = (int*)alloc(EDIM * 4);
  float* bps    = (float*)alloc(NROUTERBLK * EDIM * 4);
  (void)outeB;

  // weight conversion (independent of routing chain)
  transpose_cvt<<<dim3(HDIM / 64, DDIM / 64, EDIM), 256, 0, stream>>>(w1, w1t, DDIM, HDIM);
  transpose_cvt<<<dim3(DDIM / 64, HDIM / 64, EDIM), 256, 0, stream>>>(w2, w2t, HDIM, DDIM);

  // routing chain
  router_k<<<NROUTERBLK, 256, 0, stream>>>(x, rw, eidx, gatesA, bps);
  count_k<<<32, 256, 0, stream>>>(eidx, cc);
  scan_k<<<1, 256, 0, stream>>>(cc, bps, cb, counts, rowsN, out + (size_t)TDIM * DDIM);
  pos_k<<<32, 256, 0, stream>>>(eidx, gatesA, cb, posa, wslotA);
  scatter_k<<<NSLOT, 64, 0, stream>>>(x, eidx, posa, buf);

  // expert GEMM 1: (E,CAP,D) x (E,D,H) -> GELU -> (E,CAP,H)
  gemm256<DDIM, DDIM, HDIM, 1><<<dim3(HDIM / 256, CAPD / 256, EDIM), 512, 0, stream>>>(
      buf, w1t, b1, hbuf, 0, rowsN);

  // expert GEMM 2, split-K=2 in ONE dispatch (z = e + 8*ks)
  gemm256<HDIM / 2, HDIM, DDIM, 0><<<dim3(DDIM / 256, CAPD / 256, EDIM * 2), 512, 0, stream>>>(
      hbuf, w2t, b2, outeA, PSTRIDE, rowsN);

  // combine
  combine_k<<<TDIM, 256, 0, stream>>>(outeA, outeA + PSTRIDE, eidx, posa, wslotA, out);
}